// Round 15
// baseline (165.471 us; speedup 1.0000x reference)
//
#include <hip/hip_runtime.h>
#include <hip/hip_bf16.h>
#include <math.h>

#define CDIV(a,b) (((a)+(b)-1)/(b))
#define WPCV 8    // workgroups per cell for conv (64*8 = 512 blocks)
#define KCH 32    // point chunks for knn (16 per fused gather dispatch)

typedef __attribute__((ext_vector_type(8))) short bf16x8;
typedef __attribute__((ext_vector_type(4))) float f32x4;

__device__ __forceinline__ float elu_f(float x){ return x > 0.f ? x : expm1f(x); }
__device__ __forceinline__ unsigned short f2bf(float x){
    __hip_bfloat16 h = __float2bfloat16(x);
    union { __hip_bfloat16 b; unsigned short u; } cv; cv.b = h; return cv.u;
}
__device__ __forceinline__ float bf2f(unsigned short u){
    unsigned int ui = ((unsigned int)u) << 16;
    union { unsigned int u; float f; } cv; cv.u = ui; return cv.f;
}

// ---------------- zero deg + cellcnt (replaces pathologically slow runtime fill) ----------------
__global__ void k_zero(int* __restrict__ p, int n)
{
    int i = blockIdx.x * blockDim.x + threadIdx.x;
    if (i < n) p[i] = 0;
}

// ---------------- fused: basis/hist/deg/rank + pos_x preprocess + x->bf16 ----------------
__global__ void k_basis_px(const float* __restrict__ ea, const int* __restrict__ dst,
                        float* __restrict__ basis, int* __restrict__ cellid,
                        int* __restrict__ cellcnt, int* __restrict__ deg,
                        int* __restrict__ rank, int E, int EB, int PB,
                        const float* __restrict__ posx, const int* __restrict__ bx,
                        float4* __restrict__ px4, int N,
                        const float* __restrict__ x, unsigned short* __restrict__ xbf)
{
    const int tid = threadIdx.x;
    const int bid = blockIdx.x;
    if (bid >= EB) {
        int r = bid - EB;
        if (r < PB) {                      // ---- px part ----
            int n = r*256 + tid;
            if (n < N) {
                float off = (float)bx[n] * 1e5f;
                float a = posx[n*3+0]+off, b = posx[n*3+1]+off, c = posx[n*3+2]+off;
                px4[n] = make_float4(a, b, c, a*a + b*b + c*c);
            }
        } else {                           // ---- x -> bf16 (8 elems/thread) ----
            int i = (r - PB)*256 + tid;
            if (i < N*8) {
                const float4* xs = (const float4*)x + (size_t)i*2;
                float4 a4 = xs[0], b4 = xs[1];
                bf16x8 v;
                v[0]=(short)f2bf(a4.x); v[1]=(short)f2bf(a4.y);
                v[2]=(short)f2bf(a4.z); v[3]=(short)f2bf(a4.w);
                v[4]=(short)f2bf(b4.x); v[5]=(short)f2bf(b4.y);
                v[6]=(short)f2bf(b4.z); v[7]=(short)f2bf(b4.w);
                *(bf16x8*)(xbf + (size_t)i*8) = v;
            }
        }
        return;
    }
    // ---- basis part ----
    __shared__ int hist[64];
    if (tid < 64) hist[tid] = 0;
    __syncthreads();
    int e = bid * 256 + tid;
    if (e < E) {
        float f[3]; int bi[3];
        #pragma unroll
        for (int d = 0; d < 3; d++) {
            float v = ea[e*3+d] * 4.f;      // K-1 = 4
            float b = floorf(v);
            f[d] = v - b;
            int bb = (int)b; bb = bb < 0 ? 0 : (bb > 3 ? 3 : bb);
            bi[d] = bb;
        }
        int cell = bi[0] + 4*bi[1] + 16*bi[2];
        cellid[e] = cell;
        atomicAdd(&hist[cell], 1);
        rank[e] = atomicAdd(deg + dst[e], 1);
        float bs[8];
        #pragma unroll
        for (int c = 0; c < 8; c++) {
            float b = 1.f;
            #pragma unroll
            for (int d = 0; d < 3; d++)
                b *= ((c>>d)&1) ? f[d] : (1.f - f[d]);
            bs[c] = b;
        }
        float4* bw = (float4*)(basis + (size_t)e*8);
        bw[0] = make_float4(bs[0],bs[1],bs[2],bs[3]);
        bw[1] = make_float4(bs[4],bs[5],bs[6],bs[7]);
    }
    __syncthreads();
    if (tid < 64 && hist[tid]) atomicAdd(cellcnt + tid, hist[tid]);
}

// ---------------- degree prefix scan (one block) + invdeg + cell scan ----------------
__global__ __launch_bounds__(1024) void k_degscan(const int* __restrict__ deg,
                        int* __restrict__ csr, float* __restrict__ invdeg, int N,
                        const int* __restrict__ cellcnt, int* __restrict__ cellstart,
                        int* __restrict__ cellfill)
{
    __shared__ int buf[2][1024];
    const int t = threadIdx.x;
    if (t < 64) {                          // 64-cell prefix scan in wave 0
        int v = cellcnt[t];
        int s = v;
        #pragma unroll
        for (int off = 1; off < 64; off <<= 1) {
            int o = __shfl_up(s, off, 64);
            if (t >= off) s += o;
        }
        cellstart[t] = s - v; cellfill[t] = s - v;
        if (t == 63) cellstart[64] = s;
    }
    const int base = t*8;
    int loc[8]; int s = 0;
    #pragma unroll
    for (int j = 0; j < 8; j++) {
        loc[j] = s;
        int d = (base+j < N) ? deg[base+j] : 0;
        if (base+j < N) invdeg[base+j] = 1.f / fmaxf((float)d, 1.f);
        s += d;
    }
    buf[0][t] = s; __syncthreads();
    int pb = 0;
    for (int off = 1; off < 1024; off <<= 1) {
        int v = buf[pb][t];
        if (t >= off) v += buf[pb][t-off];
        buf[pb^1][t] = v; __syncthreads(); pb ^= 1;
    }
    int excl = buf[pb][t] - s;
    #pragma unroll
    for (int j = 0; j < 8; j++)
        if (base+j < N) csr[base+j] = excl + loc[j];
    if (t == 0) csr[N] = buf[pb][1023];
}

// ---------------- fused: scatter + dstpos + wprep ----------------
__global__ __launch_bounds__(256) void k_pack(
    const int* __restrict__ cellid, int* __restrict__ fill, int* __restrict__ elist,
    const int* __restrict__ dst, const int* __restrict__ rank,
    const int* __restrict__ csr, int* __restrict__ dstpos, int E, int SB,
    const float* __restrict__ Wa, const float* __restrict__ Wb,
    unsigned short* __restrict__ WTa, unsigned short* __restrict__ WTb)
{
    __shared__ float shbuf[64*65];
    const int tid = threadIdx.x;
    const int bid = blockIdx.x;
    if (bid < SB) {                        // ---- scatter ----
        int* hist = (int*)shbuf;
        int* bas  = hist + 64;
        if (tid < 64) hist[tid] = 0;
        __syncthreads();
        int e = bid * 256 + tid;
        int cell = 0, loc = 0;
        bool act = e < E;
        if (act) { cell = cellid[e]; loc = atomicAdd(&hist[cell], 1); }
        __syncthreads();
        if (tid < 64) bas[tid] = hist[tid] ? atomicAdd(fill + tid, hist[tid]) : 0;
        __syncthreads();
        if (act) elist[bas[cell] + loc] = e;
    } else if (bid < 2*SB) {               // ---- dstpos: e -> slot in dst-sorted order ----
        int e = (bid - SB) * 256 + tid;
        if (e < E) dstpos[e] = csr[dst[e]] + rank[e];
    } else {                               // ---- wprep ----
        int b = bid - 2*SB;
        float (*ws65)[65] = (float(*)[65])shbuf;
        const float* Wsrc = (b < 125) ? (Wa + (size_t)b*4096) : (Wb + (size_t)(b-125)*4096);
        unsigned short* Wdst = (b < 125) ? (WTa + (size_t)b*4096) : (WTb + (size_t)(b-125)*4096);
        #pragma unroll
        for (int j = 0; j < 16; j++) {
            int idx = j*256 + tid;             // idx = i*64 + o
            ws65[idx>>6][idx&63] = Wsrc[idx];
        }
        __syncthreads();
        #pragma unroll
        for (int j = 0; j < 16; j++) {
            int idx = j*256 + tid;             // idx = o*64 + i
            int o = idx>>6, i = idx&63;
            Wdst[idx] = f2bf(ws65[i][o]);
        }
    }
}

// ---------------- spline conv: MFMA, W8 in LDS, bf16 input, ye dst-sorted ----------------
__global__ __launch_bounds__(256) void k_conv(
    const unsigned short* __restrict__ xin, const unsigned short* __restrict__ WT,
    const int* __restrict__ elist, const int* __restrict__ cellstart,
    const float* __restrict__ basis, const int* __restrict__ src,
    const int* __restrict__ dstpos, unsigned short* __restrict__ ye)
{
    __shared__ unsigned short wt[8][64][64];   // [corner][out][in] bf16, row-swizzled
    __shared__ unsigned short xb[64][64];      // [edge][in] bf16, row-swizzled
    __shared__ float bts[8][64];               // [corner][edge]
    __shared__ int dpos[64];

    const int cell = blockIdx.x / WPCV;
    const int sub  = blockIdx.x % WPCV;
    const int tid  = threadIdx.x;
    const int w    = tid >> 6;
    const int lane = tid & 63;
    const int eh   = w >> 1;       // edge half (0/1)
    const int oh   = w & 1;        // out half (0/1)
    const int l15  = lane & 15;
    const int kgrp = lane >> 4;    // 0..3
    const int swz  = lane & 7;

    int kc[8];
    {
        int b0 = cell & 3, b1 = (cell >> 2) & 3, b2 = (cell >> 4) & 3;
        #pragma unroll
        for (int c = 0; c < 8; c++)
            kc[c] = (b0 + (c&1)) + 5*(b1 + ((c>>1)&1)) + 25*(b2 + ((c>>2)&1));
    }

    #pragma unroll
    for (int j = 0; j < 16; j++) {
        int cj  = j >> 1;
        int off = ((j & 1) << 8) + tid;
        int row = off >> 3, colc = off & 7;
        bf16x8 v = ((const bf16x8*)(WT + (size_t)kc[cj]*4096))[off];
        *(bf16x8*)&wt[cj][row][(colc ^ (row & 7)) << 3] = v;
    }

    const int s0 = cellstart[cell], s1 = cellstart[cell+1];
    const int se = tid >> 2, sm = tid & 3;

    for (int base = s0 + sub*64; base < s1; base += WPCV*64) {
        int ne = s1 - base; ne = ne > 64 ? 64 : ne;
        __syncthreads();
        int c0 = (sm*2)     ^ (se & 7);
        int c1 = (sm*2 + 1) ^ (se & 7);
        if (se < ne) {
            int eid = elist[base + se];
            int sn  = src[eid];
            const bf16x8* xr = (const bf16x8*)(xin + (size_t)sn*64);
            bf16x8 v0 = xr[sm*2], v1 = xr[sm*2+1];
            *(bf16x8*)&xb[se][c0 << 3] = v0;
            *(bf16x8*)&xb[se][c1 << 3] = v1;
            if (sm == 0) {
                const float4* br = (const float4*)(basis + (size_t)eid*8);
                float4 bA = br[0], bB = br[1];
                bts[0][se]=bA.x; bts[1][se]=bA.y; bts[2][se]=bA.z; bts[3][se]=bA.w;
                bts[4][se]=bB.x; bts[5][se]=bB.y; bts[6][se]=bB.z; bts[7][se]=bB.w;
                dpos[se] = dstpos[eid];
            }
        } else {
            bf16x8 z = {0,0,0,0,0,0,0,0};
            *(bf16x8*)&xb[se][c0 << 3] = z;
            *(bf16x8*)&xb[se][c1 << 3] = z;
            if (sm == 0) dpos[se] = -1;
        }
        __syncthreads();

        bf16x8 a[2][2];
        #pragma unroll
        for (int me = 0; me < 2; me++) {
            int arow = eh*32 + me*16 + l15;
            #pragma unroll
            for (int kh = 0; kh < 2; kh++)
                a[me][kh] = *(const bf16x8*)&xb[arow][((kh*4 + kgrp) ^ swz) << 3];
        }

        f32x4 y[2][2] = {{{0,0,0,0},{0,0,0,0}},{{0,0,0,0},{0,0,0,0}}};
        #pragma unroll
        for (int c = 0; c < 8; c++) {
            float4 bv[2];
            bv[0] = *(const float4*)&bts[c][eh*32 +      (kgrp << 2)];
            bv[1] = *(const float4*)&bts[c][eh*32 + 16 + (kgrp << 2)];
            bf16x8 bfr[2][2];
            #pragma unroll
            for (int nb = 0; nb < 2; nb++) {
                int brow = oh*32 + nb*16 + l15;
                #pragma unroll
                for (int kh = 0; kh < 2; kh++)
                    bfr[nb][kh] = *(const bf16x8*)&wt[c][brow][((kh*4 + kgrp) ^ swz) << 3];
            }
            #pragma unroll
            for (int me = 0; me < 2; me++) {
                #pragma unroll
                for (int nb = 0; nb < 2; nb++) {
                    f32x4 t = {0.f, 0.f, 0.f, 0.f};
                    t = __builtin_amdgcn_mfma_f32_16x16x32_bf16(a[me][0], bfr[nb][0], t, 0, 0, 0);
                    t = __builtin_amdgcn_mfma_f32_16x16x32_bf16(a[me][1], bfr[nb][1], t, 0, 0, 0);
                    y[me][nb][0] = fmaf(bv[me].x, t[0], y[me][nb][0]);
                    y[me][nb][1] = fmaf(bv[me].y, t[1], y[me][nb][1]);
                    y[me][nb][2] = fmaf(bv[me].z, t[2], y[me][nb][2]);
                    y[me][nb][3] = fmaf(bv[me].w, t[3], y[me][nb][3]);
                }
            }
        }
        #pragma unroll
        for (int me = 0; me < 2; me++) {
            #pragma unroll
            for (int r = 0; r < 4; r++) {
                int el = eh*32 + me*16 + (kgrp << 2) + r;
                int dp = dpos[el];
                if (dp >= 0) {
                    unsigned short* yp = ye + (size_t)dp*64 + oh*32 + l15;
                    yp[0]  = f2bf(y[me][0][r]);
                    yp[16] = f2bf(y[me][1][r]);
                }
            }
        }
    }
}

// ---------------- fused: gather (mean+root+bias+ELU) + knn_part half ----------------
// blocks [0, KB): knn chunks [chbase, chbase+16); blocks [KB, KB+GB): gather.
// knn blocks first = long-running; gather blocks backfill CU capacity.
__global__ __launch_bounds__(256) void k_gather_knn(
    const unsigned short* __restrict__ ye, const int* __restrict__ csr,
    const unsigned short* __restrict__ xin, const float* __restrict__ root,
    const float* __restrict__ bias, const float* __restrict__ invdeg,
    unsigned short* __restrict__ hout, int N, int KB,
    const float4* __restrict__ px4, const float* __restrict__ posy,
    const int* __restrict__ by, float* __restrict__ pd, int* __restrict__ pi,
    int Npts, int Ny, int chbase)
{
    __shared__ float sh[4][64];
    const int bid = blockIdx.x;
    const int tid = threadIdx.x;

    if (bid < KB) {
        // ---- knn_part (round-8 proven body, scalar point loads) ----
        const int qb  = (bid / 16) * 256;
        const int ch  = chbase + (bid % 16);
        const int NC  = Npts / KCH;            // 256
        const int q = qb + tid;
        float off = (float)by[q] * 1e5f;
        float qa = posy[q*3+0]+off, qbv = posy[q*3+1]+off, qc = posy[q*3+2]+off;
        float sy = qa*qa + qbv*qbv + qc*qc;
        float qa2 = -2.f*qa, qb2 = -2.f*qbv, qc2 = -2.f*qc;

        const float4* __restrict__ pts = px4 + (size_t)ch * NC;
        const int gbase = ch * NC;

        float d0 = 3.4e38f, d1 = 3.4e38f, d2s = 3.4e38f;
        int   i0 = 0x7fffffff, i1 = 0x7fffffff, i2 = 0x7fffffff;
        #pragma unroll 16
        for (int p = 0; p < NC; p++) {
            float4 pt = pts[p];                  // uniform -> scalar load
            float u  = fmaf(qa2, pt.x, fmaf(qb2, pt.y, fmaf(qc2, pt.z, sy + pt.w)));
            int   gi = gbase + p;
            bool c0 = u < d0, c1 = u < d1, c2 = u < d2s;
            float nd0 = fminf(d0, u);
            float nd1 = __builtin_amdgcn_fmed3f(d0, u, d1);
            float nd2 = __builtin_amdgcn_fmed3f(u, d1, d2s);
            i2 = c1 ? i1 : (c2 ? gi : i2);       // uses old i1
            i1 = c0 ? i0 : (c1 ? gi : i1);       // uses old i0
            i0 = c0 ? gi : i0;
            d0 = nd0; d1 = nd1; d2s = nd2;
        }
        size_t ob = ((size_t)ch*Ny + q)*3;
        pd[ob+0]=d0; pd[ob+1]=d1; pd[ob+2]=d2s;
        pi[ob+0]=i0; pi[ob+1]=i1; pi[ob+2]=i2;
        return;
    }

    // ---- gather ----
    const int w = tid >> 6, lane = tid & 63;
    const int n = (bid - KB)*4 + w;
    if (n >= N) return;
    const int s0 = csr[n], s1 = csr[n+1];
    const int j8 = lane >> 3, c8 = lane & 7;
    float acc[8] = {};
    for (int base = s0; base < s1; base += 8) {
        int ei = base + j8;
        if (ei < s1) {
            bf16x8 v = *(const bf16x8*)(ye + (size_t)ei*64 + c8*8);
            #pragma unroll
            for (int k = 0; k < 8; k++)
                acc[k] += bf2f((unsigned short)v[k]);
        }
    }
    #pragma unroll
    for (int m = 8; m <= 32; m <<= 1) {
        #pragma unroll
        for (int k = 0; k < 8; k++)
            acc[k] += __shfl_xor(acc[k], m, 64);
    }
    if (j8 == 0) {
        #pragma unroll
        for (int k = 0; k < 8; k++) sh[w][c8*8+k] = acc[k];
    }
    float aggr = sh[w][lane];            // same-wave LDS write->read
    float av = aggr * invdeg[n];
    float xv = bf2f(xin[(size_t)n*64 + lane]);
    float rt = bias[lane];
    #pragma unroll 8
    for (int i = 0; i < 64; i++)
        rt = fmaf(__shfl(xv, i, 64), root[i*64 + lane], rt);
    hout[(size_t)n*64 + lane] = f2bf(elu_f(av + rt));
}

// ---------------- 3-NN merge: 96 candidates + interpolate (bf16 h2) ----------------
__global__ __launch_bounds__(256) void k_knn_merge(
    const float* __restrict__ pd, const int* __restrict__ pi,
    const unsigned short* __restrict__ h2, float* __restrict__ out, int Ny)
{
    const int w = threadIdx.x >> 6, lane = threadIdx.x & 63;
    const int q = blockIdx.x*4 + w;
    float a0 = 3.4e38f, a1 = 3.4e38f, a2 = 3.4e38f;
    int   b0 = 0x7fffffff, b1 = 0x7fffffff, b2 = 0x7fffffff;
    if (lane < KCH) {
        size_t base = ((size_t)lane*Ny + q)*3;
        a0 = pd[base+0]; a1 = pd[base+1]; a2 = pd[base+2];
        b0 = pi[base+0]; b1 = pi[base+1]; b2 = pi[base+2];
    }
    float rd[3]; int ri[3];
    #pragma unroll
    for (int j = 0; j < 3; j++) {
        float md = a0; int mi = b0;
        #pragma unroll
        for (int s = 1; s < 64; s <<= 1) {
            float od = __shfl_xor(md, s, 64);
            int   oi = __shfl_xor(mi, s, 64);
            if (od < md || (od == md && oi < mi)) { md = od; mi = oi; }
        }
        rd[j] = md; ri[j] = mi;
        if (b0 == mi) { a0=a1; b0=b1; a1=a2; b1=b2; a2=3.4e38f; b2=0x7fffffff; }
    }
    float w0 = 1.f/fmaxf(rd[0], 1e-16f);
    float w1 = 1.f/fmaxf(rd[1], 1e-16f);
    float w2 = 1.f/fmaxf(rd[2], 1e-16f);
    float ws = w0 + w1 + w2;
    float v = w0*bf2f(h2[(size_t)ri[0]*64+lane]) + w1*bf2f(h2[(size_t)ri[1]*64+lane])
            + w2*bf2f(h2[(size_t)ri[2]*64+lane]);
    out[(size_t)q*64+lane] = v / ws;
}

extern "C" void kernel_launch(void* const* d_in, const int* in_sizes, int n_in,
                              void* d_out, int out_size, void* d_ws, size_t ws_size,
                              hipStream_t stream)
{
    const float* x     = (const float*)d_in[0];
    const int*   ei    = (const int*)d_in[1];
    const float* ea    = (const float*)d_in[2];
    const float* posx  = (const float*)d_in[3];
    const int*   bx    = (const int*)d_in[4];
    const float* posy  = (const float*)d_in[5];
    const int*   by    = (const int*)d_in[6];
    const float* Wa    = (const float*)d_in[7];
    const float* roota = (const float*)d_in[8];
    const float* biasa = (const float*)d_in[9];
    const float* Wb    = (const float*)d_in[10];
    const float* rootb = (const float*)d_in[11];
    const float* biasb = (const float*)d_in[12];

    const int N  = in_sizes[0] / 64;
    const int E  = in_sizes[1] / 2;
    const int Ny = in_sizes[5] / 3;
    const int* srcp = ei;
    const int* dstp = ei + E;

    char* ws = (char*)d_ws;
    size_t off = 0;
    auto alloc = [&](size_t bytes) { void* p = ws + off; off += (bytes + 255) & ~255ull; return p; };
    float*  basis    = (float*)alloc((size_t)E*8*4);
    int*    cellid   = (int*)  alloc((size_t)E*4);
    int*    rank     = (int*)  alloc((size_t)E*4);
    int*    elist    = (int*)  alloc((size_t)E*4);
    int*    dstpos   = (int*)  alloc((size_t)E*4);
    int*    deg      = (int*)  alloc((size_t)N*4);     // deg + cellcnt contiguous: one k_zero
    int*    cellcnt  = (int*)  alloc(64*4);
    int*    csr      = (int*)  alloc((size_t)(N+1)*4);
    float*  invdeg   = (float*)alloc((size_t)N*4);
    int*    cellstart= (int*)  alloc(65*4);
    int*    cellfill = (int*)  alloc(64*4);
    unsigned short* xbf = (unsigned short*)alloc((size_t)N*64*2);
    unsigned short* h1  = (unsigned short*)alloc((size_t)N*64*2);
    unsigned short* h2  = (unsigned short*)alloc((size_t)N*64*2);
    float4* px4      = (float4*)alloc((size_t)N*16);
    unsigned short* WTa = (unsigned short*)alloc((size_t)125*4096*2);
    unsigned short* WTb = (unsigned short*)alloc((size_t)125*4096*2);
    unsigned short* ye  = (unsigned short*)alloc((size_t)E*64*2);
    float* pd = (float*)alloc((size_t)Ny*KCH*3*4);   // no aliasing: gather reads ye concurrently
    int*   pi = (int*)  alloc((size_t)Ny*KCH*3*4);
    (void)ws_size; (void)n_in; (void)out_size;

    const int EB = CDIV(E,256);        // 512
    const int PB = CDIV(N,256);        // 32
    const int XB = CDIV(N*8,256);      // 256 (x->bf16, 8 elems/thread)
    const int GB = CDIV(N,4);          // 2048 gather blocks
    const int KB = (Ny/256)*16;        // 1024 knn blocks per half
    const int ZN = N + 64;             // deg + cellcnt (contiguous)

    k_zero    <<<CDIV(ZN,256), 256, 0, stream>>>(deg, ZN);
    k_basis_px<<<EB+PB+XB, 256, 0, stream>>>(ea, dstp, basis, cellid, cellcnt, deg, rank,
                                             E, EB, PB, posx, bx, px4, N, x, xbf);
    k_degscan <<<1, 1024, 0, stream>>>(deg, csr, invdeg, N, cellcnt, cellstart, cellfill);
    k_pack    <<<2*EB + 250, 256, 0, stream>>>(cellid, cellfill, elist, dstp, rank,
                                               csr, dstpos, E, EB, Wa, Wb, WTa, WTb);

    k_conv      <<<64*WPCV, 256, 0, stream>>>(xbf, WTa, elist, cellstart, basis, srcp, dstpos, ye);
    k_gather_knn<<<KB+GB, 256, 0, stream>>>(ye, csr, xbf, roota, biasa, invdeg, h1, N, KB,
                                            px4, posy, by, pd, pi, N, Ny, 0);

    k_conv      <<<64*WPCV, 256, 0, stream>>>(h1, WTb, elist, cellstart, basis, srcp, dstpos, ye);
    k_gather_knn<<<KB+GB, 256, 0, stream>>>(ye, csr, h1, rootb, biasb, invdeg, h2, N, KB,
                                            px4, posy, by, pd, pi, N, Ny, 16);

    k_knn_merge<<<Ny/4, 256, 0, stream>>>(pd, pi, h2, (float*)d_out, Ny);
}